// Round 8
// baseline (537.850 us; speedup 1.0000x reference)
//
#include <hip/hip_runtime.h>

typedef _Float16 f16;
typedef __attribute__((ext_vector_type(8))) _Float16 half8;
typedef __attribute__((ext_vector_type(4))) _Float16 half4v;
typedef __attribute__((ext_vector_type(4))) float floatx4;

#define T_DIM 2048
#define HID   2048
#define NH    16
#define HD    128
#define QG_LD 2064
#define SM_SCALE 0.08838834764831845f   // 1/sqrt(128)
#define NEG_BIG  -1e30f

// ---------------------------------------------------------------- async copy
__device__ __forceinline__ void async16(const void* g, void* l) {
  __builtin_amdgcn_global_load_lds((const __attribute__((address_space(1))) void*)g,
                                   (__attribute__((address_space(3))) void*)l, 16, 0, 0);
}

// ------------------------------------------------- fp32 -> fp16 transpose (weights)
__global__ __launch_bounds__(256) void transpose_w(const float* __restrict__ src, int src_ld,
                                                   f16* __restrict__ dst) {
  __shared__ float tile[32][33];
  const int bx = blockIdx.x * 32, by = blockIdx.y * 32;
  const int tx = threadIdx.x, ty = threadIdx.y;
#pragma unroll
  for (int i = 0; i < 4; ++i)
    tile[ty + 8 * i][tx] = src[(size_t)(by + ty + 8 * i) * src_ld + bx + tx];
  __syncthreads();
#pragma unroll
  for (int i = 0; i < 4; ++i)
    dst[(size_t)(bx + ty + 8 * i) * HID + by + tx] = (f16)tile[tx][ty + 8 * i];
}

// ------------------------------------------------- fp16 -> fp16 transpose (V)
__global__ __launch_bounds__(256) void transpose_h(const f16* __restrict__ src, f16* __restrict__ dst) {
  __shared__ f16 tile[32][33];
  const int bx = blockIdx.x * 32, by = blockIdx.y * 32;
  const int tx = threadIdx.x, ty = threadIdx.y;
#pragma unroll
  for (int i = 0; i < 4; ++i)
    tile[ty + 8 * i][tx] = src[(size_t)(by + ty + 8 * i) * T_DIM + bx + tx];
  __syncthreads();
#pragma unroll
  for (int i = 0; i < 4; ++i)
    dst[(size_t)(bx + ty + 8 * i) * T_DIM + by + tx] = tile[tx][ty + 8 * i];
}

// ------------------------------------------------- fp32 -> fp16 convert (hidden)
__global__ __launch_bounds__(256) void convert_f32_f16(const float* __restrict__ src, f16* __restrict__ dst) {
  const int i = (blockIdx.x * 256 + threadIdx.x) * 4;
  const float4 v = *(const float4*)(src + i);
  half4v o;
  o.x = (f16)v.x; o.y = (f16)v.y; o.z = (f16)v.z; o.w = (f16)v.w;
  *(half4v*)(dst + i) = o;
}

// ------------------------------------------------- gate: fp64 dot, sign only matters
__global__ __launch_bounds__(256) void gate_kernel(const float* __restrict__ hidden,
                                                   const float* __restrict__ Wq,
                                                   float* __restrict__ gate) {
  __shared__ double red[256][16];
  const int t = blockIdx.x, tid = threadIdx.x;
  double sums[16];
#pragma unroll
  for (int h2 = 0; h2 < 16; ++h2) sums[h2] = 0.0;
  const float* hrow = hidden + (size_t)t * HID;
  for (int k = tid; k < HID; k += 256) {
    const double hv = (double)hrow[k];
    const float* wr = Wq + (size_t)k * QG_LD + 2048;
#pragma unroll
    for (int h2 = 0; h2 < 16; ++h2) sums[h2] += hv * (double)wr[h2];
  }
#pragma unroll
  for (int h2 = 0; h2 < 16; ++h2) red[tid][h2] = sums[h2];
  __syncthreads();
  for (int st = 128; st > 0; st >>= 1) {
    if (tid < st) {
#pragma unroll
      for (int h2 = 0; h2 < 16; ++h2) red[tid][h2] += red[tid + st][h2];
    }
    __syncthreads();
  }
  if (tid < 16) gate[(size_t)t * 16 + tid] = (red[0][tid] > 0.0) ? 1.f : 0.f;
}

// ------------------------------------------------- RMSNorm(full 2048) + RoPE -> fp16
__global__ __launch_bounds__(256) void norm_rope(const float* __restrict__ src, const float* __restrict__ w,
                                                 const int* __restrict__ pos, f16* __restrict__ dst) {
  __shared__ float row[2048];
  __shared__ float red[256];
  const int t = blockIdx.x, tid = threadIdx.x;
  const float* s = src + (size_t)t * HID;
  float ss = 0.f;
#pragma unroll
  for (int e = 0; e < 8; ++e) {
    float v = s[tid + 256 * e];
    row[tid + 256 * e] = v;
    ss += v * v;
  }
  red[tid] = ss;
  __syncthreads();
  for (int st = 128; st > 0; st >>= 1) {
    if (tid < st) red[tid] += red[tid + st];
    __syncthreads();
  }
  const float scl = rsqrtf(red[0] * (1.f / 2048.f) + 1e-6f);
  const float p = (float)pos[t];
#pragma unroll
  for (int e = 0; e < 8; ++e) {
    const int idx = tid + 256 * e;
    const int d = idx & 127;
    const int dh = d & 63;
    const int pidx = (d < 64) ? idx + 64 : idx - 64;
    const float xn = row[idx] * scl * w[idx];
    const float xp = row[pidx] * scl * w[pidx];
    const float inv = __expf(-(float)dh * 0.20503692772194388f);
    float cs, sn;
    sincosf(p * inv, &sn, &cs);
    const float o = (d < 64) ? (xn * cs - xp * sn) : (xn * cs + xp * sn);
    dst[(size_t)t * HID + idx] = (f16)o;
  }
}

// ------------------------------------------------- register-direct GEMM core (no LDS, no barriers)
// A: MxK row-major fp16.  Bt: NxK row-major fp16.  Fragments loaded straight from
// global: one 64-lane half8 load touches 16 rows x one fully-used 64-B line.
// 2-stage software pipeline at kk=32 granularity; accumulation order identical
// to the LDS version (k ascending) -> bit-identical results.
__device__ __forceinline__ void reg_gemm_core(const f16* __restrict__ A, const f16* __restrict__ Bt,
                                              floatx4 (&acc)[4][4], int kbase, int klen) {
  const int tid = threadIdx.x;
  const int lane = tid & 63, wave = tid >> 6;
  const int m0 = blockIdx.y * 128, n0 = blockIdx.x * 128;
  const int mo = (wave >> 1) * 64, no = (wave & 1) * 64;
  const int cn = lane & 15, q16 = lane >> 4;

  const f16* pa[4];
  const f16* pb[4];
#pragma unroll
  for (int i = 0; i < 4; ++i) {
    pa[i] = A + (size_t)(m0 + mo + i * 16 + cn) * 2048 + q16 * 8;
    pb[i] = Bt + (size_t)(n0 + no + i * 16 + cn) * 2048 + q16 * 8;
  }

  half8 fa[2][4], fb[2][4];
#pragma unroll
  for (int i = 0; i < 4; ++i) {
    fa[0][i] = *(const half8*)(pa[i] + kbase);
    fb[0][i] = *(const half8*)(pb[i] + kbase);
  }
  const int kend = kbase + klen;
  for (int k = kbase; k < kend; k += 64) {
#pragma unroll
    for (int hf = 0; hf < 2; ++hf) {
      const int nx = hf ^ 1;
      const int knext = k + 32 * (hf + 1);
      if (knext < kend) {
#pragma unroll
        for (int i = 0; i < 4; ++i) {
          fa[nx][i] = *(const half8*)(pa[i] + knext);
          fb[nx][i] = *(const half8*)(pb[i] + knext);
        }
      }
#pragma unroll
      for (int i = 0; i < 4; ++i)
#pragma unroll
        for (int j = 0; j < 4; ++j)
          acc[i][j] = __builtin_amdgcn_mfma_f32_16x16x32_f16(fa[hf][i], fb[hf][j], acc[i][j], 0, 0, 0);
    }
  }
}

__global__ __launch_bounds__(256, 3) void gemm_qkv(const f16* __restrict__ A,
                                                   const f16* __restrict__ B0, const f16* __restrict__ B1,
                                                   const f16* __restrict__ B2,
                                                   float* __restrict__ C0, float* __restrict__ C1,
                                                   f16* __restrict__ C2) {
  const int z = blockIdx.z;
  const f16* Bt = (z == 0) ? B0 : ((z == 1) ? B1 : B2);
  floatx4 acc[4][4] = {};
  reg_gemm_core(A, Bt, acc, 0, 2048);
  const int lane = threadIdx.x & 63, wave = threadIdx.x >> 6;
  const int mb = blockIdx.y * 128 + (wave >> 1) * 64;
  const int nb = blockIdx.x * 128 + (wave & 1) * 64;
  const int r0 = (lane >> 4) * 4, cn = lane & 15;
  if (z == 2) {
#pragma unroll
    for (int i = 0; i < 4; ++i)
#pragma unroll
      for (int j = 0; j < 4; ++j)
#pragma unroll
        for (int r = 0; r < 4; ++r)
          C2[(size_t)(mb + i * 16 + r0 + r) * 2048 + nb + j * 16 + cn] = (f16)acc[i][j][r];
  } else {
    float* C = z ? C1 : C0;
#pragma unroll
    for (int i = 0; i < 4; ++i)
#pragma unroll
      for (int j = 0; j < 4; ++j)
#pragma unroll
        for (int r = 0; r < 4; ++r)
          C[(size_t)(mb + i * 16 + r0 + r) * 2048 + nb + j * 16 + cn] = acc[i][j][r];
  }
}

// split-K=2 attention-output GEMM: z picks K-half, writes fp32 partial
__global__ __launch_bounds__(256, 3) void gemm_out_sk(const f16* __restrict__ A, const f16* __restrict__ Bt,
                                                      float* __restrict__ P0, float* __restrict__ P1) {
  const int z = blockIdx.z;
  floatx4 acc[4][4] = {};
  reg_gemm_core(A, Bt, acc, z * 1024, 1024);
  float* C = z ? P1 : P0;
  const int lane = threadIdx.x & 63, wave = threadIdx.x >> 6;
  const int mb = blockIdx.y * 128 + (wave >> 1) * 64;
  const int nb = blockIdx.x * 128 + (wave & 1) * 64;
  const int r0 = (lane >> 4) * 4, cn = lane & 15;
#pragma unroll
  for (int i = 0; i < 4; ++i)
#pragma unroll
    for (int j = 0; j < 4; ++j)
#pragma unroll
      for (int r = 0; r < 4; ++r)
        C[(size_t)(mb + i * 16 + r0 + r) * 2048 + nb + j * 16 + cn] = acc[i][j][r];
}

__global__ __launch_bounds__(256) void add_out(const float* __restrict__ P0, const float* __restrict__ P1,
                                               float* __restrict__ out) {
  const int i = (blockIdx.x * 256 + threadIdx.x) * 4;
  const float4 a = *(const float4*)(P0 + i);
  const float4 b = *(const float4*)(P1 + i);
  float4 o;
  o.x = a.x + b.x; o.y = a.y + b.y; o.z = a.z + b.z; o.w = a.w + b.w;
  *(float4*)(out + i) = o;
}

// ------------------------------------------------- dual flash attention (round-3, passing)
__global__ __launch_bounds__(256, 2) void flash_kernel(const f16* __restrict__ Qg, const f16* __restrict__ Kg,
                                                       const f16* __restrict__ VTg, const float* __restrict__ gate,
                                                       f16* __restrict__ Oa) {
  __shared__ __align__(16) f16 Ks[2][64 * 128];    // [s][d]
  __shared__ __align__(16) f16 VTs[2][128 * 64];   // [d][s]
  __shared__ __align__(16) f16 Ps[4][16][72];      // wave-private, 144B stride: aligned + 2-way max

  const int tid = threadIdx.x;
  const int lane = tid & 63, wv = tid >> 6;
  const int q16 = lane >> 4, cn = lane & 15;
  const int r0 = q16 * 4;

  const int p = blockIdx.x;
  const int xcd = p & 7;
  const int idx = p >> 3;
  const int h = (xcd << 1) | (idx & 1);
  const int rest = idx >> 1;
  const int qt = (rest < 16) ? rest : 47 - rest;
  const int t0 = qt * 64;

  half8 qa[4];
#pragma unroll
  for (int i = 0; i < 4; ++i)
    qa[i] = *(const half8*)(Qg + (size_t)(t0 + 16 * wv + cn) * HID + h * HD + 32 * i + q16 * 8);

#pragma unroll
  for (int i = 0; i < 4; ++i) {
    const int rk = 16 * i + 4 * wv + q16;
    async16(Kg + (size_t)rk * HID + h * HD + cn * 8, (char*)Ks[0] + 4096 * i + 1024 * wv);
    const int rv = 32 * i + 8 * wv + (lane >> 3);
    async16(VTg + (size_t)(h * HD + rv) * T_DIM + (lane & 7) * 8, (char*)VTs[0] + 4096 * i + 1024 * wv);
  }

  floatx4 og[8] = {}, ol[8] = {};
  float mg[4], lg[4], ll[4];
#pragma unroll
  for (int r = 0; r < 4; ++r) { mg[r] = NEG_BIG; lg[r] = 0.f; ll[r] = 0.f; }

  int cur = 0;
  for (int kt = 0; kt <= qt; ++kt) {
    const int s0 = kt * 64;
    __syncthreads();
    if (kt < qt) {
      const int sn = s0 + 64;
#pragma unroll
      for (int i = 0; i < 4; ++i) {
        const int rk = 16 * i + 4 * wv + q16;
        async16(Kg + (size_t)(sn + rk) * HID + h * HD + cn * 8, (char*)Ks[cur ^ 1] + 4096 * i + 1024 * wv);
        const int rv = 32 * i + 8 * wv + (lane >> 3);
        async16(VTg + (size_t)(h * HD + rv) * T_DIM + sn + (lane & 7) * 8, (char*)VTs[cur ^ 1] + 4096 * i + 1024 * wv);
      }
    }

    floatx4 sacc[4] = {};
#pragma unroll
    for (int i = 0; i < 4; ++i)
#pragma unroll
      for (int nt = 0; nt < 4; ++nt) {
        half8 b = *(const half8*)&Ks[cur][(nt * 16 + cn) * 128 + 32 * i + q16 * 8];
        sacc[nt] = __builtin_amdgcn_mfma_f32_16x16x32_f16(qa[i], b, sacc[nt], 0, 0, 0);
      }

    const bool diag = (kt == qt);
    const bool dolocal = (kt + 2 >= qt);

    float pe[4][4];
    float rmax[4], rsum[4], lsum[4], alpha[4];
#pragma unroll
    for (int nt = 0; nt < 4; ++nt)
#pragma unroll
      for (int r = 0; r < 4; ++r) {
        float x = sacc[nt][r] * SM_SCALE;
        if (diag && (s0 + nt * 16 + cn > t0 + wv * 16 + r0 + r)) x = NEG_BIG;
        pe[nt][r] = x;
      }
#pragma unroll
    for (int r = 0; r < 4; ++r)
      rmax[r] = fmaxf(fmaxf(pe[0][r], pe[1][r]), fmaxf(pe[2][r], pe[3][r]));
#pragma unroll
    for (int off = 1; off < 16; off <<= 1)
#pragma unroll
      for (int r = 0; r < 4; ++r) rmax[r] = fmaxf(rmax[r], __shfl_xor(rmax[r], off, 64));
#pragma unroll
    for (int r = 0; r < 4; ++r) {
      const float mn = fmaxf(mg[r], rmax[r]);
      alpha[r] = __expf(mg[r] - mn);
      mg[r] = mn;
      rsum[r] = 0.f;
      lsum[r] = 0.f;
    }
#pragma unroll
    for (int nt = 0; nt < 4; ++nt)
#pragma unroll
      for (int r = 0; r < 4; ++r) {
        const float e = __expf(pe[nt][r] - mg[r]);
        Ps[wv][r0 + r][nt * 16 + cn] = (f16)e;
        rsum[r] += e;
        pe[nt][r] = e;
      }
    if (dolocal) {
#pragma unroll
      for (int nt = 0; nt < 4; ++nt)
#pragma unroll
        for (int r = 0; r < 4; ++r)
          if ((t0 + wv * 16 + r0 + r) - (s0 + nt * 16 + cn) < 128) lsum[r] += pe[nt][r];
#pragma unroll
      for (int off = 1; off < 16; off <<= 1)
#pragma unroll
        for (int r = 0; r < 4; ++r) lsum[r] += __shfl_xor(lsum[r], off, 64);
    }
#pragma unroll
    for (int off = 1; off < 16; off <<= 1)
#pragma unroll
      for (int r = 0; r < 4; ++r) rsum[r] += __shfl_xor(rsum[r], off, 64);
#pragma unroll
    for (int r = 0; r < 4; ++r) {
      lg[r] = lg[r] * alpha[r] + rsum[r];
      ll[r] = ll[r] * alpha[r] + lsum[r];
    }
#pragma unroll
    for (int dt = 0; dt < 8; ++dt)
#pragma unroll
      for (int r = 0; r < 4; ++r) { og[dt][r] *= alpha[r]; ol[dt][r] *= alpha[r]; }

    const int tloc = t0 + wv * 16 + cn;
#pragma unroll
    for (int kk = 0; kk < 64; kk += 32) {
      half8 ag = *(const half8*)&Ps[wv][cn][kk + q16 * 8];
      if (dolocal) {
        half8 al;
#pragma unroll
        for (int j = 0; j < 8; ++j) {
          const int s = s0 + kk + q16 * 8 + j;
          al[j] = (tloc - s < 128) ? ag[j] : (f16)0;
        }
#pragma unroll
        for (int dt = 0; dt < 8; ++dt) {
          half8 b = *(const half8*)&VTs[cur][(dt * 16 + cn) * 64 + kk + q16 * 8];
          og[dt] = __builtin_amdgcn_mfma_f32_16x16x32_f16(ag, b, og[dt], 0, 0, 0);
          ol[dt] = __builtin_amdgcn_mfma_f32_16x16x32_f16(al, b, ol[dt], 0, 0, 0);
        }
      } else {
#pragma unroll
        for (int dt = 0; dt < 8; ++dt) {
          half8 b = *(const half8*)&VTs[cur][(dt * 16 + cn) * 64 + kk + q16 * 8];
          og[dt] = __builtin_amdgcn_mfma_f32_16x16x32_f16(ag, b, og[dt], 0, 0, 0);
        }
      }
    }
    cur ^= 1;
  }

  float gsel[4];
#pragma unroll
  for (int r = 0; r < 4; ++r) gsel[r] = gate[(size_t)(t0 + wv * 16 + r0 + r) * NH + h];
#pragma unroll
  for (int dt = 0; dt < 8; ++dt)
#pragma unroll
    for (int r = 0; r < 4; ++r) {
      const float v = (gsel[r] > 0.5f) ? (og[dt][r] / lg[r]) : (ol[dt][r] / ll[r]);
      Oa[(size_t)(t0 + wv * 16 + r0 + r) * HID + h * HD + dt * 16 + cn] = (f16)v;
    }
}

// ------------------------------------------------------------------ host (identical to round 7)
extern "C" void kernel_launch(void* const* d_in, const int* in_sizes, int n_in,
                              void* d_out, int out_size, void* d_ws, size_t ws_size,
                              hipStream_t stream) {
  const float* hidden = (const float*)d_in[0];
  const int* pos = (const int*)d_in[1];
  const float* Wq = (const float*)d_in[2];
  const float* Wk = (const float*)d_in[3];
  const float* Wv = (const float*)d_in[4];
  const float* Wo = (const float*)d_in[5];
  const float* qw = (const float*)d_in[6];
  const float* kw = (const float*)d_in[7];

  char* ws = (char*)d_ws;
  const size_t MB = 1ull << 20;
  // Peak footprint 88.125 MB — identical to passing rounds 1/3/7.
  f16* WqT = (f16*)(ws + 0 * MB);         // 8 MB; reused as WoT
  f16* WkT = (f16*)(ws + 8 * MB);         // 8 MB; dead after QKV
  f16* WvT = (f16*)(ws + 16 * MB);        // 8 MB; dead after QKV
  f16* hidh = (f16*)(ws + 24 * MB);       // 8 MB
  float* q_raw = (float*)(ws + 32 * MB);  // 16 MB; front 8 MB reused as attn
  float* k_raw = (float*)(ws + 48 * MB);  // 16 MB; front 8 MB reused as vT
  f16* v_h = (f16*)(ws + 64 * MB);        // 8 MB
  f16* q_h = (f16*)(ws + 72 * MB);        // 8 MB; dead after flash
  f16* k_h = (f16*)(ws + 80 * MB);        // 8 MB; dead after flash
  float* gate = (float*)(ws + 88 * MB);   // 128 KB
  f16* WoT = WqT;
  f16* attn = (f16*)q_raw;
  f16* vT = (f16*)k_raw;
  float* P0 = (float*)(ws + 8 * MB);      // 16 MB over WkT+WvT (dead at use)
  float* P1 = (float*)(ws + 72 * MB);     // 16 MB over q_h+k_h (dead at use)

  dim3 tb(32, 8);
  dim3 tg(64, 64);
  transpose_w<<<tg, tb, 0, stream>>>(Wq, 2064, WqT);
  transpose_w<<<tg, tb, 0, stream>>>(Wk, 2048, WkT);
  transpose_w<<<tg, tb, 0, stream>>>(Wv, 2048, WvT);
  convert_f32_f16<<<4096, 256, 0, stream>>>(hidden, hidh);
  gate_kernel<<<2048, 256, 0, stream>>>(hidden, Wq, gate);
  gemm_qkv<<<dim3(16, 16, 3), 256, 0, stream>>>(hidh, WqT, WkT, WvT, q_raw, k_raw, v_h);
  transpose_w<<<tg, tb, 0, stream>>>(Wo, 2048, WoT);
  norm_rope<<<2048, 256, 0, stream>>>(q_raw, qw, pos, q_h);
  norm_rope<<<2048, 256, 0, stream>>>(k_raw, kw, pos, k_h);
  transpose_h<<<tg, tb, 0, stream>>>(v_h, vT);
  flash_kernel<<<512, 256, 0, stream>>>(q_h, k_h, vT, gate, attn);
  gemm_out_sk<<<dim3(16, 16, 2), 256, 0, stream>>>(attn, WoT, P0, P1);
  add_out<<<4096, 256, 0, stream>>>(P0, P1, (float*)d_out);
}

// Round 9
// 408.097 us; speedup vs baseline: 1.3179x; 1.3179x over previous
//
#include <hip/hip_runtime.h>

typedef _Float16 f16;
typedef __attribute__((ext_vector_type(8))) _Float16 half8;
typedef __attribute__((ext_vector_type(4))) _Float16 half4v;
typedef __attribute__((ext_vector_type(4))) float floatx4;

#define T_DIM 2048
#define HID   2048
#define NH    16
#define HD    128
#define QG_LD 2064
#define SM_SCALE 0.08838834764831845f   // 1/sqrt(128)
#define NEG_BIG  -1e30f

// ---------------------------------------------------------------- async copy
__device__ __forceinline__ void async16(const void* g, void* l) {
  __builtin_amdgcn_global_load_lds((const __attribute__((address_space(1))) void*)g,
                                   (__attribute__((address_space(3))) void*)l, 16, 0, 0);
}

// ------------------------------------------------- fused QKV weight transpose (z selects)
__global__ __launch_bounds__(256) void transpose_all(const float* __restrict__ Wq,
                                                     const float* __restrict__ Wk,
                                                     const float* __restrict__ Wv,
                                                     f16* __restrict__ WqT, f16* __restrict__ WkT,
                                                     f16* __restrict__ WvT) {
  __shared__ float tile[32][33];
  const int z = blockIdx.z;
  const float* src = (z == 0) ? Wq : ((z == 1) ? Wk : Wv);
  const int ld = (z == 0) ? QG_LD : 2048;
  f16* dst = (z == 0) ? WqT : ((z == 1) ? WkT : WvT);
  const int bx = blockIdx.x * 32, by = blockIdx.y * 32;
  const int tx = threadIdx.x, ty = threadIdx.y;
#pragma unroll
  for (int i = 0; i < 4; ++i)
    tile[ty + 8 * i][tx] = src[(size_t)(by + ty + 8 * i) * ld + bx + tx];
  __syncthreads();
#pragma unroll
  for (int i = 0; i < 4; ++i)
    dst[(size_t)(bx + ty + 8 * i) * HID + by + tx] = (f16)tile[tx][ty + 8 * i];
}

// ------------------------------------------------- fp32 -> fp16 transpose (Wo)
__global__ __launch_bounds__(256) void transpose_w(const float* __restrict__ src, int src_ld,
                                                   f16* __restrict__ dst) {
  __shared__ float tile[32][33];
  const int bx = blockIdx.x * 32, by = blockIdx.y * 32;
  const int tx = threadIdx.x, ty = threadIdx.y;
#pragma unroll
  for (int i = 0; i < 4; ++i)
    tile[ty + 8 * i][tx] = src[(size_t)(by + ty + 8 * i) * src_ld + bx + tx];
  __syncthreads();
#pragma unroll
  for (int i = 0; i < 4; ++i)
    dst[(size_t)(bx + ty + 8 * i) * HID + by + tx] = (f16)tile[tx][ty + 8 * i];
}

// ------------------------------------------------- fp16 -> fp16 transpose (V)
__global__ __launch_bounds__(256) void transpose_h(const f16* __restrict__ src, f16* __restrict__ dst) {
  __shared__ f16 tile[32][33];
  const int bx = blockIdx.x * 32, by = blockIdx.y * 32;
  const int tx = threadIdx.x, ty = threadIdx.y;
#pragma unroll
  for (int i = 0; i < 4; ++i)
    tile[ty + 8 * i][tx] = src[(size_t)(by + ty + 8 * i) * T_DIM + bx + tx];
  __syncthreads();
#pragma unroll
  for (int i = 0; i < 4; ++i)
    dst[(size_t)(bx + ty + 8 * i) * T_DIM + by + tx] = tile[tx][ty + 8 * i];
}

// ------------------------------------------------- fp32 -> fp16 convert (hidden)
__global__ __launch_bounds__(256) void convert_f32_f16(const float* __restrict__ src, f16* __restrict__ dst) {
  const int i = (blockIdx.x * 256 + threadIdx.x) * 4;
  const float4 v = *(const float4*)(src + i);
  half4v o;
  o.x = (f16)v.x; o.y = (f16)v.y; o.z = (f16)v.z; o.w = (f16)v.w;
  *(half4v*)(dst + i) = o;
}

// ------------------------------------------------- gate: fp64 dot, sign only matters
__global__ __launch_bounds__(256) void gate_kernel(const float* __restrict__ hidden,
                                                   const float* __restrict__ Wq,
                                                   float* __restrict__ gate) {
  __shared__ double red[256][16];
  const int t = blockIdx.x, tid = threadIdx.x;
  double sums[16];
#pragma unroll
  for (int h2 = 0; h2 < 16; ++h2) sums[h2] = 0.0;
  const float* hrow = hidden + (size_t)t * HID;
  for (int k = tid; k < HID; k += 256) {
    const double hv = (double)hrow[k];
    const float* wr = Wq + (size_t)k * QG_LD + 2048;
#pragma unroll
    for (int h2 = 0; h2 < 16; ++h2) sums[h2] += hv * (double)wr[h2];
  }
#pragma unroll
  for (int h2 = 0; h2 < 16; ++h2) red[tid][h2] = sums[h2];
  __syncthreads();
  for (int st = 128; st > 0; st >>= 1) {
    if (tid < st) {
#pragma unroll
      for (int h2 = 0; h2 < 16; ++h2) red[tid][h2] += red[tid + st][h2];
    }
    __syncthreads();
  }
  if (tid < 16) gate[(size_t)t * 16 + tid] = (red[0][tid] > 0.0) ? 1.f : 0.f;
}

// ------------------------------------------------- RMSNorm(full 2048) + RoPE (q & k fused, f16 in)
__global__ __launch_bounds__(256) void norm_rope2(const f16* __restrict__ qsrc, const f16* __restrict__ ksrc,
                                                  const float* __restrict__ qw, const float* __restrict__ kw,
                                                  const int* __restrict__ pos,
                                                  f16* __restrict__ qdst, f16* __restrict__ kdst) {
  __shared__ float row[2048];
  __shared__ float red[256];
  const int t = blockIdx.x & 2047, sel = blockIdx.x >> 11, tid = threadIdx.x;
  const f16* s = (sel ? ksrc : qsrc) + (size_t)t * HID;
  const float* w = sel ? kw : qw;
  f16* dst = sel ? kdst : qdst;
  float ss = 0.f;
#pragma unroll
  for (int e = 0; e < 8; ++e) {
    float v = (float)s[tid + 256 * e];
    row[tid + 256 * e] = v;
    ss += v * v;
  }
  red[tid] = ss;
  __syncthreads();
  for (int st = 128; st > 0; st >>= 1) {
    if (tid < st) red[tid] += red[tid + st];
    __syncthreads();
  }
  const float scl = rsqrtf(red[0] * (1.f / 2048.f) + 1e-6f);
  const float p = (float)pos[t];
#pragma unroll
  for (int e = 0; e < 8; ++e) {
    const int idx = tid + 256 * e;
    const int d = idx & 127;
    const int dh = d & 63;
    const int pidx = (d < 64) ? idx + 64 : idx - 64;
    const float xn = row[idx] * scl * w[idx];
    const float xp = row[pidx] * scl * w[pidx];
    const float inv = __expf(-(float)dh * 0.20503692772194388f);
    float cs, sn;
    sincosf(p * inv, &sn, &cs);
    const float o = (d < 64) ? (xn * cs - xp * sn) : (xn * cs + xp * sn);
    dst[(size_t)t * HID + idx] = (f16)o;
  }
}

// ------------------------------------------------- GEMM 128x128xBK64, double-buffered (R7 proven)
__device__ __forceinline__ void gemm_issue(const f16* __restrict__ A, const f16* __restrict__ Bt,
                                           char* As, char* Bs, int m0, int n0, int k0,
                                           int wave, int srow, int scol) {
#pragma unroll
  for (int i = 0; i < 4; ++i) {
    async16(A + (size_t)(m0 + 32 * i + srow) * 2048 + k0 + scol, As + 4096 * i + 1024 * wave);
    async16(Bt + (size_t)(n0 + 32 * i + srow) * 2048 + k0 + scol, Bs + 4096 * i + 1024 * wave);
  }
}

__device__ __forceinline__ void gemm_core_db(const f16* __restrict__ A, const f16* __restrict__ Bt,
                                             f16* As, f16* Bs, floatx4 (&acc)[4][4],
                                             int kbase, int klen) {
  const int tid = threadIdx.x;
  const int lane = tid & 63, wave = tid >> 6;
  const int m0 = blockIdx.y * 128, n0 = blockIdx.x * 128;
  const int mo = (wave >> 1) * 64, no = (wave & 1) * 64;
  const int cn = lane & 15, q16 = lane >> 4;
  const int srow = 8 * wave + (lane >> 3);
  const int scol = (lane & 7) * 8;
  gemm_issue(A, Bt, (char*)As, (char*)Bs, m0, n0, kbase, wave, srow, scol);
  int cur = 0;
  for (int k0 = kbase; k0 < kbase + klen; k0 += 64) {
    __syncthreads();
    if (k0 + 64 < kbase + klen)
      gemm_issue(A, Bt, (char*)(As + (cur ^ 1) * 8192), (char*)(Bs + (cur ^ 1) * 8192),
                 m0, n0, k0 + 64, wave, srow, scol);
    const f16* as = As + cur * 8192;
    const f16* bs = Bs + cur * 8192;
#pragma unroll
    for (int kk = 0; kk < 64; kk += 32) {
      half8 av[4], bv[4];
#pragma unroll
      for (int i = 0; i < 4; ++i) av[i] = *(const half8*)&as[(mo + i * 16 + cn) * 64 + kk + q16 * 8];
#pragma unroll
      for (int i = 0; i < 4; ++i) bv[i] = *(const half8*)&bs[(no + i * 16 + cn) * 64 + kk + q16 * 8];
#pragma unroll
      for (int i = 0; i < 4; ++i)
#pragma unroll
        for (int j = 0; j < 4; ++j)
          acc[i][j] = __builtin_amdgcn_mfma_f32_16x16x32_f16(av[i], bv[j], acc[i][j], 0, 0, 0);
    }
    cur ^= 1;
  }
}

// fused QKV: all outputs f16 now (q/k re-read only by norm_rope2)
__global__ __launch_bounds__(256, 2) void gemm_qkv(const f16* __restrict__ A,
                                                   const f16* __restrict__ B0, const f16* __restrict__ B1,
                                                   const f16* __restrict__ B2,
                                                   f16* __restrict__ C0, f16* __restrict__ C1,
                                                   f16* __restrict__ C2) {
  __shared__ __align__(16) f16 As[2 * 128 * 64];
  __shared__ __align__(16) f16 Bs[2 * 128 * 64];
  const int z = blockIdx.z;
  const f16* Bt = (z == 0) ? B0 : ((z == 1) ? B1 : B2);
  f16* C = (z == 0) ? C0 : ((z == 1) ? C1 : C2);
  floatx4 acc[4][4] = {};
  gemm_core_db(A, Bt, As, Bs, acc, 0, 2048);
  const int lane = threadIdx.x & 63, wave = threadIdx.x >> 6;
  const int mb = blockIdx.y * 128 + (wave >> 1) * 64;
  const int nb = blockIdx.x * 128 + (wave & 1) * 64;
  const int r0 = (lane >> 4) * 4, cn = lane & 15;
#pragma unroll
  for (int i = 0; i < 4; ++i)
#pragma unroll
    for (int j = 0; j < 4; ++j)
#pragma unroll
      for (int r = 0; r < 4; ++r)
        C[(size_t)(mb + i * 16 + r0 + r) * 2048 + nb + j * 16 + cn] = (f16)acc[i][j][r];
}

// split-K=2 attention-output GEMM: z picks K-half, writes fp32 partial
__global__ __launch_bounds__(256, 2) void gemm_out_sk(const f16* __restrict__ A, const f16* __restrict__ Bt,
                                                      float* __restrict__ P0, float* __restrict__ P1) {
  __shared__ __align__(16) f16 As[2 * 128 * 64];
  __shared__ __align__(16) f16 Bs[2 * 128 * 64];
  const int z = blockIdx.z;
  floatx4 acc[4][4] = {};
  gemm_core_db(A, Bt, As, Bs, acc, z * 1024, 1024);
  float* C = z ? P1 : P0;
  const int lane = threadIdx.x & 63, wave = threadIdx.x >> 6;
  const int mb = blockIdx.y * 128 + (wave >> 1) * 64;
  const int nb = blockIdx.x * 128 + (wave & 1) * 64;
  const int r0 = (lane >> 4) * 4, cn = lane & 15;
#pragma unroll
  for (int i = 0; i < 4; ++i)
#pragma unroll
    for (int j = 0; j < 4; ++j)
#pragma unroll
      for (int r = 0; r < 4; ++r)
        C[(size_t)(mb + i * 16 + r0 + r) * 2048 + nb + j * 16 + cn] = acc[i][j][r];
}

__global__ __launch_bounds__(256) void add_out(const float* __restrict__ P0, const float* __restrict__ P1,
                                               float* __restrict__ out) {
  const int i = (blockIdx.x * 256 + threadIdx.x) * 4;
  const float4 a = *(const float4*)(P0 + i);
  const float4 b = *(const float4*)(P1 + i);
  float4 o;
  o.x = a.x + b.x; o.y = a.y + b.y; o.z = a.z + b.z; o.w = a.w + b.w;
  *(float4*)(out + i) = o;
}

// ------------------------------------------------- dual flash attention v3: gate-select single-accumulator
// Since global and local softmax share the running max (shift-invariance), and each row's
// output uses exactly one of them (hard gate), select at P-store time:
//   P_sel = exp(S - m) * (gate_row | in_window)
// -> ONE accumulator, ONE PV MFMA set. l computed by an extra MFMA with B=ones
// (row-sum in the accumulator, same alpha rescale) -- removes the rsum shuffle-reduce.
// Numerics identical to the R3 path that passed (same shift, same f16 P).
__global__ __launch_bounds__(256, 2) void flash_kernel(const f16* __restrict__ Qg, const f16* __restrict__ Kg,
                                                       const f16* __restrict__ VTg, const float* __restrict__ gate,
                                                       f16* __restrict__ Oa) {
  __shared__ __align__(16) f16 Ks[2][64 * 128];    // [s][d]
  __shared__ __align__(16) f16 VTs[2][128 * 64];   // [d][s]
  __shared__ __align__(16) f16 Ps[4][16][72];      // wave-private, 144B stride: aligned + 2-way max

  const int tid = threadIdx.x;
  const int lane = tid & 63, wv = tid >> 6;
  const int q16 = lane >> 4, cn = lane & 15;
  const int r0 = q16 * 4;

  const int p = blockIdx.x;
  const int xcd = p & 7;
  const int idx = p >> 3;
  const int h = (xcd << 1) | (idx & 1);
  const int rest = idx >> 1;
  const int qt = (rest < 16) ? rest : 47 - rest;
  const int t0 = qt * 64;

  bool gbit[4];
#pragma unroll
  for (int r = 0; r < 4; ++r)
    gbit[r] = gate[(size_t)(t0 + wv * 16 + r0 + r) * NH + h] > 0.5f;

  half8 qa[4];
#pragma unroll
  for (int i = 0; i < 4; ++i)
    qa[i] = *(const half8*)(Qg + (size_t)(t0 + 16 * wv + cn) * HID + h * HD + 32 * i + q16 * 8);

#pragma unroll
  for (int i = 0; i < 4; ++i) {
    const int rk = 16 * i + 4 * wv + q16;
    async16(Kg + (size_t)rk * HID + h * HD + cn * 8, (char*)Ks[0] + 4096 * i + 1024 * wv);
    const int rv = 32 * i + 8 * wv + (lane >> 3);
    async16(VTg + (size_t)(h * HD + rv) * T_DIM + (lane & 7) * 8, (char*)VTs[0] + 4096 * i + 1024 * wv);
  }

  floatx4 og[8] = {};
  floatx4 lacc = {0.f, 0.f, 0.f, 0.f};
  float mg[4];
#pragma unroll
  for (int r = 0; r < 4; ++r) mg[r] = NEG_BIG;

  const half8 ones = {(f16)1, (f16)1, (f16)1, (f16)1, (f16)1, (f16)1, (f16)1, (f16)1};

  int cur = 0;
  for (int kt = 0; kt <= qt; ++kt) {
    const int s0 = kt * 64;
    __syncthreads();
    if (kt < qt) {
      const int sn = s0 + 64;
#pragma unroll
      for (int i = 0; i < 4; ++i) {
        const int rk = 16 * i + 4 * wv + q16;
        async16(Kg + (size_t)(sn + rk) * HID + h * HD + cn * 8, (char*)Ks[cur ^ 1] + 4096 * i + 1024 * wv);
        const int rv = 32 * i + 8 * wv + (lane >> 3);
        async16(VTg + (size_t)(h * HD + rv) * T_DIM + sn + (lane & 7) * 8, (char*)VTs[cur ^ 1] + 4096 * i + 1024 * wv);
      }
    }

    // S = Q K^T : wave wv owns rows [16wv, 16wv+16)
    floatx4 sacc[4] = {};
#pragma unroll
    for (int i = 0; i < 4; ++i)
#pragma unroll
      for (int nt = 0; nt < 4; ++nt) {
        half8 b = *(const half8*)&Ks[cur][(nt * 16 + cn) * 128 + 32 * i + q16 * 8];
        sacc[nt] = __builtin_amdgcn_mfma_f32_16x16x32_f16(qa[i], b, sacc[nt], 0, 0, 0);
      }

    const bool diag = (kt == qt);

    float pe[4][4];
#pragma unroll
    for (int nt = 0; nt < 4; ++nt)
#pragma unroll
      for (int r = 0; r < 4; ++r) {
        float x = sacc[nt][r] * SM_SCALE;
        if (diag && (s0 + nt * 16 + cn > t0 + wv * 16 + r0 + r)) x = NEG_BIG;
        pe[nt][r] = x;
      }

    float rmax[4];
#pragma unroll
    for (int r = 0; r < 4; ++r)
      rmax[r] = fmaxf(fmaxf(pe[0][r], pe[1][r]), fmaxf(pe[2][r], pe[3][r]));
#pragma unroll
    for (int off = 1; off < 16; off <<= 1)
#pragma unroll
      for (int r = 0; r < 4; ++r) rmax[r] = fmaxf(rmax[r], __shfl_xor(rmax[r], off, 64));

    float alpha[4];
#pragma unroll
    for (int r = 0; r < 4; ++r) {
      const float mn = fmaxf(mg[r], rmax[r]);
      alpha[r] = __expf(mg[r] - mn);
      mg[r] = mn;
    }
#pragma unroll
    for (int dt = 0; dt < 8; ++dt)
#pragma unroll
      for (int r = 0; r < 4; ++r) og[dt][r] *= alpha[r];
#pragma unroll
    for (int r = 0; r < 4; ++r) lacc[r] *= alpha[r];

    // exp, gate/window select, store P_sel (wave-private -> no barrier)
#pragma unroll
    for (int nt = 0; nt < 4; ++nt)
#pragma unroll
      for (int r = 0; r < 4; ++r) {
        const float e = __expf(pe[nt][r] - mg[r]);   // causal-masked -> 0
        const int tt = t0 + wv * 16 + r0 + r;
        const int s = s0 + nt * 16 + cn;
        const bool keep = gbit[r] || (tt - s < 128);
        Ps[wv][r0 + r][nt * 16 + cn] = keep ? (f16)e : (f16)0.f;
      }

    // PV + row-sum: A = own P_sel rows
#pragma unroll
    for (int kk = 0; kk < 64; kk += 32) {
      half8 a = *(const half8*)&Ps[wv][cn][kk + q16 * 8];
#pragma unroll
      for (int dt = 0; dt < 8; ++dt) {
        half8 b = *(const half8*)&VTs[cur][(dt * 16 + cn) * 64 + kk + q16 * 8];
        og[dt] = __builtin_amdgcn_mfma_f32_16x16x32_f16(a, b, og[dt], 0, 0, 0);
      }
      lacc = __builtin_amdgcn_mfma_f32_16x16x32_f16(a, ones, lacc, 0, 0, 0);
    }
    cur ^= 1;
  }

  // epilogue: normalize, store f16 (selection already baked into P)
#pragma unroll
  for (int dt = 0; dt < 8; ++dt)
#pragma unroll
    for (int r = 0; r < 4; ++r) {
      const float v = og[dt][r] / lacc[r];
      Oa[(size_t)(t0 + wv * 16 + r0 + r) * HID + h * HD + dt * 16 + cn] = (f16)v;
    }
}

// ------------------------------------------------------------------ host
extern "C" void kernel_launch(void* const* d_in, const int* in_sizes, int n_in,
                              void* d_out, int out_size, void* d_ws, size_t ws_size,
                              hipStream_t stream) {
  const float* hidden = (const float*)d_in[0];
  const int* pos = (const int*)d_in[1];
  const float* Wq = (const float*)d_in[2];
  const float* Wk = (const float*)d_in[3];
  const float* Wv = (const float*)d_in[4];
  const float* Wo = (const float*)d_in[5];
  const float* qw = (const float*)d_in[6];
  const float* kw = (const float*)d_in[7];

  char* ws = (char*)d_ws;
  const size_t MB = 1ull << 20;
  // Peak footprint 88.125 MB — identical to passing rounds 1/3/7.
  f16* WqT = (f16*)(ws + 0 * MB);         // 8 MB; reused as WoT after QKV
  f16* WkT = (f16*)(ws + 8 * MB);         // 8 MB; dead after QKV
  f16* WvT = (f16*)(ws + 16 * MB);        // 8 MB; dead after QKV
  f16* hidh = (f16*)(ws + 24 * MB);       // 8 MB; dead after QKV
  f16* q_raw = (f16*)(ws + 32 * MB);      // 8 MB f16; reused as attn after norm
  f16* k_raw = (f16*)(ws + 48 * MB);      // 8 MB f16; reused as vT after norm
  f16* v_h = (f16*)(ws + 64 * MB);        // 8 MB
  f16* q_h = (f16*)(ws + 72 * MB);        // 8 MB; dead after flash
  f16* k_h = (f16*)(ws + 80 * MB);        // 8 MB; dead after flash
  float* gate = (float*)(ws + 88 * MB);   // 128 KB
  f16* WoT = WqT;
  f16* attn = q_raw;
  f16* vT = k_raw;
  float* P0 = (float*)(ws + 8 * MB);      // 16 MB over WkT+WvT (dead at use)
  float* P1 = (float*)(ws + 72 * MB);     // 16 MB over q_h+k_h (dead at use)

  dim3 tb(32, 8);
  transpose_all<<<dim3(64, 64, 3), tb, 0, stream>>>(Wq, Wk, Wv, WqT, WkT, WvT);
  convert_f32_f16<<<4096, 256, 0, stream>>>(hidden, hidh);
  gate_kernel<<<2048, 256, 0, stream>>>(hidden, Wq, gate);
  gemm_qkv<<<dim3(16, 16, 3), 256, 0, stream>>>(hidh, WqT, WkT, WvT, q_raw, k_raw, v_h);
  transpose_w<<<dim3(64, 64), tb, 0, stream>>>(Wo, 2048, WoT);
  norm_rope2<<<4096, 256, 0, stream>>>(q_raw, k_raw, qw, kw, pos, q_h, k_h);
  transpose_h<<<dim3(64, 64), tb, 0, stream>>>(v_h, vT);
  flash_kernel<<<512, 256, 0, stream>>>(q_h, k_h, vT, gate, attn);
  gemm_out_sk<<<dim3(16, 16, 2), 256, 0, stream>>>(attn, WoT, P0, P1);
  add_out<<<4096, 256, 0, stream>>>(P0, P1, (float*)d_out);
}